// Round 7
// baseline (39.260 us; speedup 1.0000x reference)
//
#include <hip/hip_runtime.h>

namespace {
constexpr int GS = 128;
constexpr int NPTS = GS * GS;          // 16384 points per grid
constexpr float RES = 0.25f;
constexpr int NGRIDS = 16;
constexpr int BLOCK = 256;
constexpr int CHUNKS = NPTS / BLOCK;   // 64 chunks per (grid,dir)
constexpr int NBLOCKS = NGRIDS * 2 * CHUNKS;  // 2048
}

// One thread per query point, 2048 blocks (32 waves/CU). Phase A: 7x7 SUPERSET
// window anchored at clamped base (rb,cb) — always in-grid, covers the true
// clamped radius-3 neighborhood, single address calc, imm-offset loads.
// Exact-done iff best <= (4*RES)^2 = 1.0 (excluded cells have Chebyshev >= 4
// -> planar >= 1.0). Phase B: wave-cooperative straggler scan, one pass with
// K = ceil(4*sqrt(bestA)) is exact. Final: per-block atomicAdd to out
// (out zeroed by a memset node in the same graph).
__global__ __launch_bounds__(BLOCK, 8) void chamfer_kernel(
    const float* __restrict__ pred, const float* __restrict__ gt,
    float* __restrict__ out)
{
    const int bid = blockIdx.x;
    const int chunk = bid & (CHUNKS - 1);
    const int pair = bid >> 6;
    const int g = pair >> 1;
    const int dir = pair & 1;
    const float* __restrict__ A  = (dir == 0) ? gt + g * NPTS : pred + g * NPTS;
    const float* __restrict__ DB = (dir == 0) ? pred + g * NPTS : gt + g * NPTS;

    const int tid = threadIdx.x;
    const int i = chunk * BLOCK + tid;
    const int ri = i >> 7;
    const int ci = i & (GS - 1);
    const float za = A[i];

    // superset window base: clamp the BASE, not each cell
    const int rb = min(max(ri, 3), GS - 4);
    const int cb = min(max(ci, 3), GS - 4);
    const float* __restrict__ wbase = DB + (rb - 3) * GS + (cb - 3);

    // per-axis planar terms
    float dx2[7], dy2[7];
    #pragma unroll
    for (int t = 0; t < 7; ++t) {
        const float dx = (float)(ri - (rb - 3 + t)) * RES;
        dx2[t] = dx * dx;
        const float dy = (float)(ci - (cb - 3 + t)) * RES;
        dy2[t] = dy * dy;
    }

    // phase A: per-row min (3 VALU/cell) then fold dx2 once per row
    float bacc[4] = {1e30f, 1e30f, 1e30f, 1e30f};
    #pragma unroll
    for (int a = 0; a < 7; ++a) {
        float rm0 = 1e30f, rm1 = 1e30f;
        #pragma unroll
        for (int b = 0; b < 7; ++b) {
            const float z = wbase[a * GS + b];          // imm offset a*512+b*4
            const float dz = za - z;
            const float v = fmaf(dz, dz, dy2[b]);
            if (b & 1) rm1 = fminf(rm1, v); else rm0 = fminf(rm0, v);
        }
        bacc[a & 3] = fminf(bacc[a & 3], fminf(rm0, rm1) + dx2[a]);
    }
    float best = fminf(fminf(bacc[0], bacc[1]), fminf(bacc[2], bacc[3]));

    // phase B: wave-cooperative straggler finish (rare)
    const int lane = tid & 63;
    const int lr = lane >> 3, lc = lane & 7;   // 8x8 lane tile
    unsigned long long pend = __ballot(best > 1.0f);
    while (pend) {
        const int src = __ffsll(pend) - 1;
        pend &= pend - 1;
        const int qri = __shfl(ri, src);
        const int qci = __shfl(ci, src);
        const float qza = __shfl(za, src);
        const float qb  = __shfl(best, src);
        int K = (int)(4.0f * sqrtf(qb)) + 1;   // >= ceil(4*sqrt(qb))
        K = min(K, GS - 1);
        float m = 1e30f;
        for (int tr = -K; tr <= K; tr += 8) {
            const int dr = tr + lr;
            if (dr > K) continue;
            const int r = min(max(qri + dr, 0), GS - 1);
            const float dx = (float)(qri - r) * RES;
            const float dxx2 = dx * dx;
            const float* __restrict__ row = DB + r * GS;
            for (int tc = -K; tc <= K; tc += 8) {
                const int dc = tc + lc;
                if (dc > K) continue;
                const int c = min(max(qci + dc, 0), GS - 1);
                const float dy = (float)(qci - c) * RES;
                const float dz = qza - row[c];
                m = fminf(m, fmaf(dz, dz, fmaf(dy, dy, dxx2)));
            }
        }
        #pragma unroll
        for (int off = 32; off > 0; off >>= 1) m = fminf(m, __shfl_xor(m, off));
        if (lane == src) best = fminf(best, m);
    }

    // block sum-reduction -> one atomicAdd per block
    for (int off = 32; off > 0; off >>= 1) best += __shfl_down(best, off);
    __shared__ float wsum[BLOCK / 64];
    if ((tid & 63) == 0) wsum[tid >> 6] = best;
    __syncthreads();
    if (tid == 0) {
        float s = 0.0f;
        #pragma unroll
        for (int w = 0; w < BLOCK / 64; ++w) s += wsum[w];
        atomicAdd(out, s * (1.0f / NGRIDS));
    }
}

extern "C" void kernel_launch(void* const* d_in, const int* in_sizes, int n_in,
                              void* d_out, int out_size, void* d_ws, size_t ws_size,
                              hipStream_t stream) {
    const float* pred = (const float*)d_in[0];  // inputs (1,1,512,512)
    const float* gt   = (const float*)d_in[1];  // targets (1,512,512)
    float* out = (float*)d_out;
    hipMemsetAsync(out, 0, sizeof(float), stream);   // graph memset node
    chamfer_kernel<<<NBLOCKS, BLOCK, 0, stream>>>(pred, gt, out);
}

// Round 8
// 16.586 us; speedup vs baseline: 2.3671x; 2.3671x over previous
//
#include <hip/hip_runtime.h>

namespace {
constexpr int GS = 128;
constexpr int NPTS = GS * GS;          // 16384 points per grid
constexpr float RES = 0.25f;
constexpr int NGRIDS = 16;
constexpr int BLOCK = 1024;
constexpr int CHUNKS = NPTS / BLOCK;   // 16 chunks per (grid,dir)
constexpr int NBLOCKS = NGRIDS * 2 * CHUNKS;  // 512
}

// One thread per query point; 512 x 1024-thread blocks (same 524288 threads,
// 4x fewer workgroups -> shorter dispatch ramp; 2 blocks/CU = 32 waves/CU).
// Phase A: 7x7 SUPERSET window at clamped base (rb,cb) — always in-grid,
// covers the clamped radius-3 neighborhood, one address calc, imm offsets.
// Exact-done iff best <= (4*RES)^2 = 1.0. Phase B: wave-cooperative straggler
// scan, one pass with K = ceil(4*sqrt(bestA)) is exact.
__global__ __launch_bounds__(BLOCK, 8) void chamfer_kernel(
    const float* __restrict__ pred, const float* __restrict__ gt,
    float* __restrict__ partial)
{
    const int bid = blockIdx.x;
    const int chunk = bid & (CHUNKS - 1);
    const int pair = bid >> 4;             // CHUNKS = 16
    const int g = pair >> 1;
    const int dir = pair & 1;
    const float* __restrict__ A  = (dir == 0) ? gt + g * NPTS : pred + g * NPTS;
    const float* __restrict__ DB = (dir == 0) ? pred + g * NPTS : gt + g * NPTS;

    const int tid = threadIdx.x;
    const int i = chunk * BLOCK + tid;
    const int ri = i >> 7;
    const int ci = i & (GS - 1);
    const float za = A[i];

    // superset window base: clamp the BASE, not each cell
    const int rb = min(max(ri, 3), GS - 4);
    const int cb = min(max(ci, 3), GS - 4);
    const float* __restrict__ wbase = DB + (rb - 3) * GS + (cb - 3);

    // per-axis planar terms
    float dx2[7], dy2[7];
    #pragma unroll
    for (int t = 0; t < 7; ++t) {
        const float dx = (float)(ri - (rb - 3 + t)) * RES;
        dx2[t] = dx * dx;
        const float dy = (float)(ci - (cb - 3 + t)) * RES;
        dy2[t] = dy * dy;
    }

    // phase A: 49 imm-offset loads off one base, per-row min folding
    float bacc[4] = {1e30f, 1e30f, 1e30f, 1e30f};
    #pragma unroll
    for (int a = 0; a < 7; ++a) {
        float rm0 = 1e30f, rm1 = 1e30f;
        #pragma unroll
        for (int b = 0; b < 7; ++b) {
            const float z = wbase[a * GS + b];          // imm offset a*512+b*4
            const float dz = za - z;
            const float v = fmaf(dz, dz, dy2[b]);
            if (b & 1) rm1 = fminf(rm1, v); else rm0 = fminf(rm0, v);
        }
        bacc[a & 3] = fminf(bacc[a & 3], fminf(rm0, rm1) + dx2[a]);
    }
    float best = fminf(fminf(bacc[0], bacc[1]), fminf(bacc[2], bacc[3]));

    // phase B: wave-cooperative straggler finish (rare)
    const int lane = tid & 63;
    const int lr = lane >> 3, lc = lane & 7;   // 8x8 lane tile
    unsigned long long pend = __ballot(best > 1.0f);
    while (pend) {
        const int src = __ffsll(pend) - 1;
        pend &= pend - 1;
        const int qri = __shfl(ri, src);
        const int qci = __shfl(ci, src);
        const float qza = __shfl(za, src);
        const float qb  = __shfl(best, src);
        int K = (int)(4.0f * sqrtf(qb)) + 1;   // >= ceil(4*sqrt(qb))
        K = min(K, GS - 1);
        float m = 1e30f;
        for (int tr = -K; tr <= K; tr += 8) {
            const int dr = tr + lr;
            if (dr > K) continue;
            const int r = min(max(qri + dr, 0), GS - 1);
            const float dx = (float)(qri - r) * RES;
            const float dxx2 = dx * dx;
            const float* __restrict__ row = DB + r * GS;
            for (int tc = -K; tc <= K; tc += 8) {
                const int dc = tc + lc;
                if (dc > K) continue;
                const int c = min(max(qci + dc, 0), GS - 1);
                const float dy = (float)(qci - c) * RES;
                const float dz = qza - row[c];
                m = fminf(m, fmaf(dz, dz, fmaf(dy, dy, dxx2)));
            }
        }
        #pragma unroll
        for (int off = 32; off > 0; off >>= 1) m = fminf(m, __shfl_xor(m, off));
        if (lane == src) best = fminf(best, m);
    }

    // block sum-reduction -> one partial per block (no atomics)
    for (int off = 32; off > 0; off >>= 1) best += __shfl_down(best, off);
    __shared__ float wsum[BLOCK / 64];
    if ((tid & 63) == 0) wsum[tid >> 6] = best;
    __syncthreads();
    if (tid == 0) {
        float s = 0.0f;
        #pragma unroll
        for (int w = 0; w < BLOCK / 64; ++w) s += wsum[w];
        partial[bid] = s;
    }
}

__global__ __launch_bounds__(512) void reduce_kernel(
    const float* __restrict__ partial, float* __restrict__ out)
{
    const int tid = threadIdx.x;
    float s = partial[tid];                // NBLOCKS = 512
    for (int off = 32; off > 0; off >>= 1) s += __shfl_down(s, off);
    __shared__ float wsum[8];
    if ((tid & 63) == 0) wsum[tid >> 6] = s;
    __syncthreads();
    if (tid == 0) {
        float t = 0.0f;
        #pragma unroll
        for (int w = 0; w < 8; ++w) t += wsum[w];
        *out = t * (1.0f / NGRIDS);
    }
}

extern "C" void kernel_launch(void* const* d_in, const int* in_sizes, int n_in,
                              void* d_out, int out_size, void* d_ws, size_t ws_size,
                              hipStream_t stream) {
    const float* pred = (const float*)d_in[0];  // inputs (1,1,512,512)
    const float* gt   = (const float*)d_in[1];  // targets (1,512,512)
    float* partial = (float*)d_ws;              // 512 floats
    float* out = (float*)d_out;
    chamfer_kernel<<<NBLOCKS, BLOCK, 0, stream>>>(pred, gt, partial);
    reduce_kernel<<<1, 512, 0, stream>>>(partial, out);
}

// Round 9
// 15.702 us; speedup vs baseline: 2.5003x; 1.0563x over previous
//
#include <hip/hip_runtime.h>

namespace {
constexpr int GS = 128;
constexpr int NPTS = GS * GS;          // 16384 points per grid
constexpr float RES = 0.25f;
constexpr int NGRIDS = 16;
constexpr int BLOCK = 1024;
constexpr int ROWS_PER_BLOCK = BLOCK / GS;     // 8 query rows per block
constexpr int CHUNKS = NPTS / BLOCK;           // 16 chunks per (grid,dir)
constexpr int NBLOCKS = NGRIDS * 2 * CHUNKS;   // 512
constexpr int SLAB_ROWS = 14;                  // max rows a block's windows touch
}

// One thread per query point; 512 x 1024-thread blocks (2 blocks/CU = 32
// waves/CU). The block's <=14-row DB slab (7 KB) is staged to LDS in one
// coalesced burst (single HBM/L2 latency exposure per block); phase A's 49
// window reads are imm-offset ds_read_b32 (latency-hidden, conflict-free).
// Phase A: 7x7 SUPERSET window at clamped base (rb,cb) — always in-grid,
// covers the clamped radius-3 neighborhood. Exact-done iff best <= (4*RES)^2
// = 1.0 (excluded cells: Chebyshev >= 4 -> planar >= 1.0). Phase B:
// wave-cooperative straggler scan from GLOBAL memory (rare); one pass with
// K = ceil(4*sqrt(bestA)) is exact (radius >= K -> planar >= bestA).
__global__ __launch_bounds__(BLOCK, 8) void chamfer_kernel(
    const float* __restrict__ pred, const float* __restrict__ gt,
    float* __restrict__ partial)
{
    __shared__ float slab[SLAB_ROWS * GS];     // 7168 B

    const int bid = blockIdx.x;
    const int chunk = bid & (CHUNKS - 1);
    const int pair = bid >> 4;             // CHUNKS = 16
    const int g = pair >> 1;
    const int dir = pair & 1;
    const float* __restrict__ A  = (dir == 0) ? gt + g * NPTS : pred + g * NPTS;
    const float* __restrict__ DB = (dir == 0) ? pred + g * NPTS : gt + g * NPTS;

    const int tid = threadIdx.x;
    const int r0 = chunk * ROWS_PER_BLOCK;
    const int rlo = max(r0 - 3, 0);
    const int rhi = min(r0 + ROWS_PER_BLOCK + 2, GS - 1);  // r0+7 rows, +3 window
    const int nrow = rhi - rlo + 1;                        // <= 14

    // stage slab rows [rlo..rhi] as float4s: <=448 loads, fully coalesced
    if (tid < nrow * (GS / 4)) {
        const int row = tid >> 5;          // GS/4 = 32 quads per row
        const int c4  = tid & 31;
        reinterpret_cast<float4*>(slab)[tid] =
            reinterpret_cast<const float4*>(DB + (rlo + row) * GS)[c4];
    }
    __syncthreads();

    const int i = chunk * BLOCK + tid;
    const int ri = r0 + (tid >> 7);
    const int ci = tid & (GS - 1);
    const float za = A[i];

    // superset window base: clamp the BASE, not each cell
    const int rb = min(max(ri, 3), GS - 4);
    const int cb = min(max(ci, 3), GS - 4);
    // rb-3 >= rlo always (rb >= 3 and rb >= r0 when r0 >= 3)
    const float* __restrict__ wbase = slab + (rb - 3 - rlo) * GS + (cb - 3);

    // per-axis planar terms
    float dx2[7], dy2[7];
    #pragma unroll
    for (int t = 0; t < 7; ++t) {
        const float dx = (float)(ri - (rb - 3 + t)) * RES;
        dx2[t] = dx * dx;
        const float dy = (float)(ci - (cb - 3 + t)) * RES;
        dy2[t] = dy * dy;
    }

    // phase A: 49 ds_read_b32 with imm offsets off one base; per-row min fold
    float bacc[4] = {1e30f, 1e30f, 1e30f, 1e30f};
    #pragma unroll
    for (int a = 0; a < 7; ++a) {
        float rm0 = 1e30f, rm1 = 1e30f;
        #pragma unroll
        for (int b = 0; b < 7; ++b) {
            const float z = wbase[a * GS + b];      // ds imm offset a*512+b*4
            const float dz = za - z;
            const float v = fmaf(dz, dz, dy2[b]);
            if (b & 1) rm1 = fminf(rm1, v); else rm0 = fminf(rm0, v);
        }
        bacc[a & 3] = fminf(bacc[a & 3], fminf(rm0, rm1) + dx2[a]);
    }
    float best = fminf(fminf(bacc[0], bacc[1]), fminf(bacc[2], bacc[3]));

    // phase B: wave-cooperative straggler finish (rare), from global
    const int lane = tid & 63;
    const int lr = lane >> 3, lc = lane & 7;   // 8x8 lane tile
    unsigned long long pend = __ballot(best > 1.0f);
    while (pend) {
        const int src = __ffsll(pend) - 1;
        pend &= pend - 1;
        const int qri = __shfl(ri, src);
        const int qci = __shfl(ci, src);
        const float qza = __shfl(za, src);
        const float qb  = __shfl(best, src);
        int K = (int)(4.0f * sqrtf(qb)) + 1;   // >= ceil(4*sqrt(qb))
        K = min(K, GS - 1);
        float m = 1e30f;
        for (int tr = -K; tr <= K; tr += 8) {
            const int dr = tr + lr;
            if (dr > K) continue;
            const int r = min(max(qri + dr, 0), GS - 1);
            const float dx = (float)(qri - r) * RES;
            const float dxx2 = dx * dx;
            const float* __restrict__ row = DB + r * GS;
            for (int tc = -K; tc <= K; tc += 8) {
                const int dc = tc + lc;
                if (dc > K) continue;
                const int c = min(max(qci + dc, 0), GS - 1);
                const float dy = (float)(qci - c) * RES;
                const float dz = qza - row[c];
                m = fminf(m, fmaf(dz, dz, fmaf(dy, dy, dxx2)));
            }
        }
        #pragma unroll
        for (int off = 32; off > 0; off >>= 1) m = fminf(m, __shfl_xor(m, off));
        if (lane == src) best = fminf(best, m);
    }

    // block sum-reduction -> one partial per block (no atomics)
    for (int off = 32; off > 0; off >>= 1) best += __shfl_down(best, off);
    __shared__ float wsum[BLOCK / 64];
    if ((tid & 63) == 0) wsum[tid >> 6] = best;
    __syncthreads();
    if (tid == 0) {
        float s = 0.0f;
        #pragma unroll
        for (int w = 0; w < BLOCK / 64; ++w) s += wsum[w];
        partial[bid] = s;
    }
}

__global__ __launch_bounds__(512) void reduce_kernel(
    const float* __restrict__ partial, float* __restrict__ out)
{
    const int tid = threadIdx.x;
    float s = partial[tid];                // NBLOCKS = 512
    for (int off = 32; off > 0; off >>= 1) s += __shfl_down(s, off);
    __shared__ float wsum[8];
    if ((tid & 63) == 0) wsum[tid >> 6] = s;
    __syncthreads();
    if (tid == 0) {
        float t = 0.0f;
        #pragma unroll
        for (int w = 0; w < 8; ++w) t += wsum[w];
        *out = t * (1.0f / NGRIDS);
    }
}

extern "C" void kernel_launch(void* const* d_in, const int* in_sizes, int n_in,
                              void* d_out, int out_size, void* d_ws, size_t ws_size,
                              hipStream_t stream) {
    const float* pred = (const float*)d_in[0];  // inputs (1,1,512,512)
    const float* gt   = (const float*)d_in[1];  // targets (1,512,512)
    float* partial = (float*)d_ws;              // 512 floats
    float* out = (float*)d_out;
    chamfer_kernel<<<NBLOCKS, BLOCK, 0, stream>>>(pred, gt, partial);
    reduce_kernel<<<1, 512, 0, stream>>>(partial, out);
}